// Round 23
// baseline (61.677 us; speedup 1.0000x reference)
//
#include <hip/hip_runtime.h>
#include <stdint.h>

#define D_DIM 512
#define NSTEPS 10
#define ALPHA0 0.1
#define DT_C 0.1
#define BETA_C 2.8982753492378875

typedef __attribute__((ext_vector_type(8))) short short8;
typedef __attribute__((ext_vector_type(4))) float floatx4;

__device__ __forceinline__ unsigned short f32_to_bf16(float f) {
    union { float f; uint32_t u; } v;
    v.f = f;
    uint32_t u = v.u;
    return (unsigned short)((u + 0x7FFFu + ((u >> 16) & 1u)) >> 16);
}
__device__ __forceinline__ float bf16_to_f32(unsigned short h) {
    union { uint32_t u; float f; } v;
    v.u = ((uint32_t)h) << 16;
    return v.f;
}
__device__ __forceinline__ short8 pack8(const float4 v0, const float4 v1) {
    short8 pk;
    pk[0] = (short)f32_to_bf16(v0.x); pk[1] = (short)f32_to_bf16(v0.y);
    pk[2] = (short)f32_to_bf16(v0.z); pk[3] = (short)f32_to_bf16(v0.w);
    pk[4] = (short)f32_to_bf16(v1.x); pk[5] = (short)f32_to_bf16(v1.y);
    pk[6] = (short)f32_to_bf16(v1.z); pk[7] = (short)f32_to_bf16(v1.w);
    return pk;
}

// A-form (fragment-tiled): element (r,k) at
//   half-id = (r>>5)*32 + (k>>5)*2 + ((r>>4)&1), byte ((k>>3&3)*16 + (r&15))*16 + (k&7)*2
// B-form of Y stores Y^T in A-form: value Y[k][c] lives at aform_off(c,k).
__device__ __forceinline__ size_t aform_off(int r, int k) {
    return ((size_t)((r >> 5) * 32 + (k >> 5) * 2 + ((r >> 4) & 1)) << 10)
         + (size_t)(((((k >> 3) & 3) * 16) + (r & 15)) << 4) + (size_t)((k & 7) * 2);
}
// Gtl (out_gemm format): half-id = (e>>4)*16 + (c>>5)
__device__ __forceinline__ size_t gtl_off(int e, int c) {
    return ((size_t)((e >> 4) * 16 + (c >> 5)) << 10)
         + (size_t)(((((c >> 3) & 3) * 16) + (e & 15)) << 4) + (size_t)((c & 7) * 2);
}

// ---------------------------------------------------------------------------
// prep2: M = L_rw + diag(alpha0 + p_e), written in A-form AND B-form.
// ---------------------------------------------------------------------------
__global__ __launch_bounds__(64) void prep2(
    const float* __restrict__ W,
    const float* __restrict__ prec,
    unsigned short* __restrict__ AfM,
    unsigned short* __restrict__ BfM)
{
    const int e = blockIdx.x;
    const int lane = threadIdx.x;
    const float* w = W + (size_t)e * D_DIM + lane * 8;
    const float4 v0 = *(const float4*)w;
    const float4 v1 = *(const float4*)(w + 4);
    float a[8] = { fabsf(v0.x), fabsf(v0.y), fabsf(v0.z), fabsf(v0.w),
                   fabsf(v1.x), fabsf(v1.y), fabsf(v1.z), fabsf(v1.w) };
    float s = a[0] + a[1] + a[2] + a[3] + a[4] + a[5] + a[6] + a[7];
#pragma unroll
    for (int off = 1; off < 64; off <<= 1) s += __shfl_xor(s, off, 64);
    const float inv = 1.0f / fmaxf(s, 1e-8f);
    const float madd = (float)ALPHA0 + prec[e];
    unsigned short mv[8];
#pragma unroll
    for (int j = 0; j < 8; ++j) {
        const int d = lane * 8 + j;
        float lv = ((d == e) ? 1.0f : 0.0f) - a[j] * inv;
        if (d == e) lv += madd;
        mv[j] = f32_to_bf16(lv);
    }
    short8 pk;
#pragma unroll
    for (int j = 0; j < 8; ++j) pk[j] = (short)mv[j];
    *(short8*)((char*)AfM + aform_off(e, lane * 8)) = pk;
#pragma unroll
    for (int j = 0; j < 8; ++j) {
        const int d = lane * 8 + j;
        *(unsigned short*)((char*)BfM + aform_off(d, e)) = mv[j];
    }
}

// ---------------------------------------------------------------------------
// pk<MODE>: C = X * Y (512^3 bf16 MFMA product).
// ROUND-23: 256 blocks x 64 thr (1-wave blocks, 32x32 tile) -- spreads the
// latency-bound product over 256 CUs (was 64 blocks x 4 waves = 64 CUs).
//  MODE 0: M2 = M*M                                   -> A-form + B-form
//  MODE 1: M3 = M2*M                                  -> A-form
//  MODE 2: V  = M3*B2 + (g3 I + g4 M + g5 M2)         -> B-form
//          with B2 = g6 I + g7 M + g8 M2 computed ON THE FLY from the
//          BfM/BfM2 chunks at the b-operand offsets (bit-identical to the
//          old ek kernel: f32 math, f32->bf16 round before MFMA).
//  MODE 3: G  = (1-g)I + g*(g0 I + g1 M + g2 M2 + M3*V) -> Gtl
// ---------------------------------------------------------------------------
template<int MODE>
__global__ __launch_bounds__(64) void pk(
    const unsigned short* __restrict__ Aop,
    const unsigned short* __restrict__ Bop,   // MODE 2: BfM (B2 built on the fly)
    unsigned short* __restrict__ outA,
    unsigned short* __restrict__ outB,
    const unsigned short* __restrict__ BfM,
    const unsigned short* __restrict__ BfM2,
    const float* __restrict__ prec,
    const float* __restrict__ gate_alpha,
    float ca0, float cb0, float ca1, float cb1, float ca2, float cb2,
    float ca3, float cb3, float ca4, float cb4, float ca5, float cb5)
{
    const int lane = threadIdx.x;
    const int lrow = lane & 15, q = lane >> 4;
    const int rg = blockIdx.x >> 4;      // 32-row group of output rows
    const int cg = blockIdx.x & 15;      // 32-col group of output cols

    const char* abase = (const char*)Aop + ((size_t)(rg * 32) << 10) + (size_t)lane * 16;
    const char* bbase = (const char*)Bop + ((size_t)(cg * 32) << 10) + (size_t)lane * 16;
    const char* b2base = (const char*)BfM2 + ((size_t)(cg * 32) << 10) + (size_t)lane * 16;

    // MODE 2: per-lane B2 coefficients (c fixed per half)
    float g6h[2], g7h[2], g8h[2];
    int ch[2];
    if (MODE == 2) {
#pragma unroll
        for (int h = 0; h < 2; ++h) {
            ch[h] = cg * 32 + h * 16 + lrow;
            const float p = prec[ch[h]];
            g6h[h] = ca3 + cb3 * p; g7h[h] = ca4 + cb4 * p; g8h[h] = ca5 + cb5 * p;
        }
    }

    floatx4 acc[2][2] = {};
#pragma unroll 4
    for (int kk = 0; kk < 16; ++kk) {
        const short8 av0 = *(const short8*)(abase + ((kk * 2 + 0) << 10));
        const short8 av1 = *(const short8*)(abase + ((kk * 2 + 1) << 10));
        short8 bv0, bv1;
        if (MODE == 2) {
            const short8 m0 = *(const short8*)(bbase  + ((kk * 2 + 0) << 10));
            const short8 m1 = *(const short8*)(bbase  + ((kk * 2 + 1) << 10));
            const short8 n0 = *(const short8*)(b2base + ((kk * 2 + 0) << 10));
            const short8 n1 = *(const short8*)(b2base + ((kk * 2 + 1) << 10));
#pragma unroll
            for (int u = 0; u < 8; ++u) {
                const int k = kk * 32 + q * 8 + u;
                float v0 = g7h[0] * bf16_to_f32((unsigned short)m0[u])
                         + g8h[0] * bf16_to_f32((unsigned short)n0[u]);
                if (k == ch[0]) v0 += g6h[0];
                float v1 = g7h[1] * bf16_to_f32((unsigned short)m1[u])
                         + g8h[1] * bf16_to_f32((unsigned short)n1[u]);
                if (k == ch[1]) v1 += g6h[1];
                bv0[u] = (short)f32_to_bf16(v0);
                bv1[u] = (short)f32_to_bf16(v1);
            }
        } else {
            bv0 = *(const short8*)(bbase + ((kk * 2 + 0) << 10));
            bv1 = *(const short8*)(bbase + ((kk * 2 + 1) << 10));
        }
        acc[0][0] = __builtin_amdgcn_mfma_f32_16x16x32_bf16(av0, bv0, acc[0][0], 0, 0, 0);
        acc[0][1] = __builtin_amdgcn_mfma_f32_16x16x32_bf16(av0, bv1, acc[0][1], 0, 0, 0);
        acc[1][0] = __builtin_amdgcn_mfma_f32_16x16x32_bf16(av1, bv0, acc[1][0], 0, 0, 0);
        acc[1][1] = __builtin_amdgcn_mfma_f32_16x16x32_bf16(av1, bv1, acc[1][1], 0, 0, 0);
    }

    float g = 0.f;
    if (MODE == 3) g = tanhf(gate_alpha[0]);

#pragma unroll
    for (int n = 0; n < 2; ++n) {
        const int c = cg * 32 + n * 16 + lrow;
        float g0 = 0.f, g1 = 0.f, g2 = 0.f;
        if (MODE >= 2) {
            const float p = prec[c];
            g0 = ca0 + cb0 * p; g1 = ca1 + cb1 * p; g2 = ca2 + cb2 * p;
        }
#pragma unroll
        for (int m = 0; m < 2; ++m) {
            const int eb = rg * 32 + m * 16;
#pragma unroll
            for (int j = 0; j < 4; ++j) {
                const int e = eb + q * 4 + j;
                float val = acc[m][n][j];
                if (MODE >= 2) {
                    const float Mec  = bf16_to_f32(*(const unsigned short*)((const char*)BfM  + aform_off(c, e)));
                    const float M2ec = bf16_to_f32(*(const unsigned short*)((const char*)BfM2 + aform_off(c, e)));
                    if (MODE == 2) {
                        val += g1 * Mec + g2 * M2ec;
                        if (e == c) val += g0;
                    } else {
                        val = g * (val + g1 * Mec + g2 * M2ec);
                        if (e == c) val += (1.0f - g) + g * g0;
                    }
                }
                const unsigned short h = f32_to_bf16(val);
                if (MODE == 0 || MODE == 1)
                    *(unsigned short*)((char*)outA + aform_off(e, c)) = h;
                if (MODE == 0 || MODE == 2)
                    *(unsigned short*)((char*)outB + aform_off(c, e)) = h;
                if (MODE == 3)
                    *(unsigned short*)((char*)outA + gtl_off(e, c)) = h;
            }
        }
    }
}

// ---------------------------------------------------------------------------
// out_gemm: out = H @ G^T (diag folded into G).
// ROUND-23: 32-row tiles, 512 blocks x 512 thr (8 waves). Round 22 ran 256
// blocks on 256 CUs = 1 block/CU -> H-stage (128KB HBM) never overlapped
// compute (16us vs 10.2us floor). Now 2 resident blocks/CU (32 KB LDS,
// acc[2][4]+b[4]+a ~= 90 regs, launch_bounds(512,2)) -> stage hides under
// the co-resident block's MFMA. G re-read doubles but stays in per-XCD L2.
// ---------------------------------------------------------------------------
__global__ __launch_bounds__(512, 2) void out_gemm(
    const float* __restrict__ H,              // [16384][512] f32
    const unsigned short* __restrict__ Gtl,   // tiled G, diag folded
    float* __restrict__ Out)
{
    const int cpx = gridDim.x >> 3;           // 64
    const int bid = (blockIdx.x & 7) * cpx + (blockIdx.x >> 3);
    const int r0 = bid * 32;
    const int tid = threadIdx.x;
    const int wave = tid >> 6, lane = tid & 63;
    const int lrow = lane & 15, q = lane >> 4;

    __shared__ unsigned short hlds[32 * D_DIM];  // 32 KiB, swizzled
    char* lds = (char*)hlds;

    // stage H: wave w rows [4w, 4w+4); lane covers cols [8*lane, +8)
#pragma unroll
    for (int i = 0; i < 4; ++i) {
        const int row = wave * 4 + i;
        const float* src = H + (size_t)(r0 + row) * D_DIM + lane * 8;
        const float4 v0 = *(const float4*)src;
        const float4 v1 = *(const float4*)(src + 4);
        int byte = row * 1024 + lane * 16;
        byte ^= (row & 7) << 4;
        *(short8*)(lds + byte) = pack8(v0, v1);
    }
    __syncthreads();

    // this wave's G tiles: e-groups [wave*4, wave*4+4), all 16 k-tiles
    const char* gtb = (const char*)Gtl + ((size_t)(wave * 4 * 16) << 10)
                      + ((size_t)lane << 4);

    floatx4 acc[2][4] = {};
#pragma unroll 2
    for (int kk = 0; kk < 16; ++kk) {
        short8 b[4];
#pragma unroll
        for (int n = 0; n < 4; ++n)
            b[n] = *(const short8*)(gtb + ((size_t)(n * 16 + kk) << 10));
#pragma unroll
        for (int m = 0; m < 2; ++m) {
            const int row = m * 16 + lrow;
            int byte = row * 1024 + kk * 64 + q * 16;
            byte ^= (row & 7) << 4;
            const short8 a = *(const short8*)(lds + byte);
#pragma unroll
            for (int n = 0; n < 4; ++n)
                acc[m][n] = __builtin_amdgcn_mfma_f32_16x16x32_bf16(a, b[n], acc[m][n], 0, 0, 0);
        }
    }

#pragma unroll
    for (int m = 0; m < 2; ++m) {
#pragma unroll
        for (int j = 0; j < 4; ++j) {
            const int r = r0 + m * 16 + q * 4 + j;
#pragma unroll
            for (int n = 0; n < 4; ++n) {
                const int e = wave * 64 + n * 16 + lrow;
                Out[(size_t)r * D_DIM + e] = acc[m][n][j];
            }
        }
    }
}

// ---------------------------------------------------------------------------
extern "C" void kernel_launch(void* const* d_in, const int* in_sizes, int n_in,
                              void* d_out, int out_size, void* d_ws, size_t ws_size,
                              hipStream_t stream)
{
    const float* H    = (const float*)d_in[0];   // (4,4096,512)
    const float* W    = (const float*)d_in[1];   // (512,512)
    const float* gate = (const float*)d_in[2];   // (1,)
    const float* prec = (const float*)d_in[3];   // (512,)
    float* out = (float*)d_out;
    char* ws = (char*)d_ws;

    // ---- host: exact polynomial coefficients of the 10-step settle ----
    double Pc[11] = {0}, Qc[11] = {0}, Rc[11] = {0}, Sc[11] = {0};
    Pc[0] = 1.0;
    const double dtd = DT_C, c1 = 1.0 - BETA_C * DT_C;
    for (int s = 0; s < NSTEPS; ++s) {
        double nR[11], nS[11];
        for (int k = 0; k < 11; ++k) {
            nR[k] = c1 * Rc[k] - dtd * (k > 0 ? Pc[k - 1] : 0.0);
            nS[k] = c1 * Sc[k] - dtd * (k > 0 ? Qc[k - 1] : 0.0);
        }
        nS[0] += dtd;
        for (int k = 0; k < 11; ++k) {
            Rc[k] = nR[k]; Sc[k] = nS[k];
            Pc[k] += dtd * nR[k]; Qc[k] += dtd * nS[k];
        }
    }
    float av[9], bv[9];
    for (int k = 0; k < 9; ++k) { av[k] = (float)Pc[k]; bv[k] = (float)Qc[k]; }

    // ws layout
    unsigned short* AfM  = (unsigned short*)(ws);
    unsigned short* BfM  = (unsigned short*)(ws + (512u << 10));
    unsigned short* AfM2 = (unsigned short*)(ws + (1024u << 10));
    unsigned short* BfM2 = (unsigned short*)(ws + (1536u << 10));
    unsigned short* AfM3 = (unsigned short*)(ws + (2048u << 10));
    unsigned short* BfV  = (unsigned short*)(ws + (2560u << 10));
    unsigned short* Gtl  = (unsigned short*)(ws + (3072u << 10));

    prep2<<<dim3(D_DIM), dim3(64), 0, stream>>>(W, prec, AfM, BfM);

    // M2 = M*M (both forms)
    pk<0><<<dim3(256), dim3(64), 0, stream>>>(
        AfM, BfM, AfM2, BfM2, nullptr, nullptr, nullptr, nullptr,
        0.f, 0.f, 0.f, 0.f, 0.f, 0.f, 0.f, 0.f, 0.f, 0.f, 0.f, 0.f);
    // M3 = M2*M (A-form)
    pk<1><<<dim3(256), dim3(64), 0, stream>>>(
        AfM2, BfM, AfM3, nullptr, nullptr, nullptr, nullptr, nullptr,
        0.f, 0.f, 0.f, 0.f, 0.f, 0.f, 0.f, 0.f, 0.f, 0.f, 0.f, 0.f);
    // V = M3*B2 + (g3 I + g4 M + g5 M2), B2 = g6 I + g7 M + g8 M2 on-the-fly
    pk<2><<<dim3(256), dim3(64), 0, stream>>>(
        AfM3, BfM, nullptr, BfV, BfM, BfM2, prec, nullptr,
        av[3], bv[3], av[4], bv[4], av[5], bv[5],
        av[6], bv[6], av[7], bv[7], av[8], bv[8]);
    // G = (1-g)I + g*(g0 I + g1 M + g2 M2 + M3*V)  -> Gtl
    pk<3><<<dim3(256), dim3(64), 0, stream>>>(
        AfM3, BfV, Gtl, nullptr, BfM, BfM2, prec, gate,
        av[0], bv[0], av[1], bv[1], av[2], bv[2],
        0.f, 0.f, 0.f, 0.f, 0.f, 0.f);

    out_gemm<<<dim3(16384 / 32), dim3(512), 0, stream>>>(H, Gtl, out);
}